// Round 2
// baseline (372.164 us; speedup 1.0000x reference)
//
#include <hip/hip_runtime.h>
#include <hip/hip_bf16.h>

// Problem constants (fixed by setup_inputs)
#define T_SZ 32
#define B_SZ 512
#define F_SZ 2048
#define H_SZ 2048
#define M_SZ (T_SZ * B_SZ)   // 16384 GEMM rows

// GEMM tile: BM=BN=256, BK=128, 8 waves (2M x 4N), wave tile 128x64 = 4x2 MFMA tiles.
// 4-phase-per-K-tile schedule with counted vmcnt (T3+T4) + setprio (T5), raw s_barrier
// (never __syncthreads in the main loop -> no forced vmcnt(0) drain).
// LDS is STATIC 128 KB (2 x (A 32K + B 32K)) -- no dynamic-shared opt-in, no
// hipFuncSetAttribute during graph capture (round-1 failure suspect).
#define BM 256
#define BN 256
#define BK 128
#define NT (F_SZ / BK)       // 16 K-tiles
#define BUF_BYTES  65536     // per double-buffer half: A 32 KB + B 32 KB
#define HALF_BYTES 16384     // one half-tile: 128 rows x 128 B

typedef int   i32x8  __attribute__((ext_vector_type(8)));    // 32 fp8 = 8 VGPRs (MFMA A/B frag)
typedef float f32x16 __attribute__((ext_vector_type(16)));   // 32x32 MFMA C/D frag

__device__ __forceinline__ void gload_lds16(const void* g, void* l) {
    // async global->LDS, 16 B/lane (global_load_lds_dwordx4).
    // LDS dest is wave-uniform base + lane*16; we permute the SOURCE address
    // per lane to implement the bank swizzle.
    __builtin_amdgcn_global_load_lds(
        (const __attribute__((address_space(1))) unsigned int*)g,
        (__attribute__((address_space(3))) unsigned int*)l,
        16, 0, 0);
}

__device__ __forceinline__ float bf16_bits_to_f32(unsigned short u) {
    return __uint_as_float(((unsigned)u) << 16);
}

__device__ __forceinline__ void sbar() {
    // raw barrier, fenced so the scheduler cannot move ds_read/gload across it
    __builtin_amdgcn_sched_barrier(0);
    __builtin_amdgcn_s_barrier();
    __builtin_amdgcn_sched_barrier(0);
}

// Stage one half-tile (128 rows x 128 B) via 2 x global_load_lds_dwordx4 per thread.
// LDS layout: row-major 128 B rows, 8 x 16B units per row, XOR-swizzled
// phys_unit = logical_unit ^ (row & 7). gload_lds writes linearly (base + lane*16),
// so the swizzle is applied by permuting the per-lane GLOBAL source address.
__device__ __forceinline__ void stage_half_tile(unsigned char* lds,
                                                const unsigned char* gpanel,
                                                int kbyte, int tid) {
    #pragma unroll
    for (int j = 0; j < 2; ++j) {
        int c   = j * 512 + tid;           // 0..1023 16B chunks
        int row = c >> 3;                  // 0..127
        int u   = (c & 7) ^ (row & 7);     // logical unit feeding phys slot c&7
        gload_lds16(gpanel + (size_t)row * F_SZ + kbyte + u * 16, (void*)(lds + c * 16));
    }
}

// ---------------- fp32 -> fp8 e4m3 (OCP), 8 elems/thread, optional pre-scale ----------------
__global__ __launch_bounds__(256) void cvt_fp8_kernel(const float* __restrict__ in,
                                                      unsigned int* __restrict__ out,
                                                      float scale, int n8) {
    int i = blockIdx.x * 256 + threadIdx.x;
    if (i >= n8) return;
    float4 v0 = ((const float4*)in)[2 * i];
    float4 v1 = ((const float4*)in)[2 * i + 1];
    int w0 = __builtin_amdgcn_cvt_pk_fp8_f32(v0.x * scale, v0.y * scale, 0, false);
    w0     = __builtin_amdgcn_cvt_pk_fp8_f32(v0.z * scale, v0.w * scale, w0, true);
    int w1 = __builtin_amdgcn_cvt_pk_fp8_f32(v1.x * scale, v1.y * scale, 0, false);
    w1     = __builtin_amdgcn_cvt_pk_fp8_f32(v1.z * scale, v1.w * scale, w1, true);
    ((uint2*)out)[i] = make_uint2((unsigned)w0, (unsigned)w1);
}

// ---------------- zero the row sum-of-squares accumulator (ws is poisoned 0xAA) ----------------
__global__ __launch_bounds__(256) void init_ss_kernel(float4* __restrict__ ss4) {
    ss4[blockIdx.x * 256 + threadIdx.x] = make_float4(0.f, 0.f, 0.f, 0.f);
}

// ---------------- GEMM (MX-fp8) + fused row-SS ----------------
// C[m,n] = (1/256) * sum_k A8[m,k]*B8[n,k] + bias[n];  ss[m] += sum_n C[m,n]^2 (atomic)
//
// Schedule per K-tile kt (4 phases, one per A strip mi):
//   iter-start (prev iter's end barrier already passed): ds_read B frags + af(mi=0)
//   phase mi: ds_read af(mi+1) [1-phase software pipeline] ;
//             stage: mi=0 -> A(kt+1) half0, mi=1 -> A(kt+1) half1   (into buf^1)
//                    mi=2 -> B(kt+2) half0, mi=3 -> B(kt+2) half1   (into buf, B slots
//                    are dead after this iter's phase-0 reads + >=1 barrier)
//             setprio(1); 4 x mfma_scale_32x32x64; setprio(0); s_barrier
//   iter-end: s_waitcnt vmcnt(4)  (A(kt+1) complete, B(kt+2) stays IN FLIGHT across
//             the barrier -- the counted-vmcnt lever; vmcnt(0) only at kt==NT-2)
__global__ __launch_bounds__(512, 2) void gemm_fp8_kernel(const unsigned char* __restrict__ A,   // [M_SZ,F_SZ] fp8
                                                          const unsigned char* __restrict__ Bt,  // [H_SZ,F_SZ] fp8 (x256)
                                                          const float* __restrict__ bias,        // [H_SZ]
                                                          __hip_bfloat16* __restrict__ C,        // [M_SZ,H_SZ] bf16
                                                          float* __restrict__ ss)                // [M_SZ] atomic SS
{
    __shared__ __align__(16) unsigned char smem[2 * BUF_BYTES];  // 128 KB static

    const int tid  = threadIdx.x;
    const int lane = tid & 63;
    const int wave = tid >> 6;           // 0..7
    const int wm   = wave >> 2;          // 0..1 -> 128-row half
    const int wn   = wave & 3;           // 0..3 -> 64-col quarter
    const int l31  = lane & 31;
    const int kh   = lane >> 5;          // k-half within a 64B MFMA slice

    // bijective XCD-chunk swizzle: 512 blocks, XCD k (= flat%8) gets logical ids
    // [k*64, k*64+64) -> an 8x8 patch of tiles: 8 A-panels + all 8 B-panels
    // cycle within one XCD's 4 MB L2 (B resident, A panel resident across its 8 uses).
    const int flat = blockIdx.y * 8 + blockIdx.x;
    const int swz  = (flat & 7) * 64 + (flat >> 3);
    const int n0   = (swz & 7) * BN;
    const int m0   = (swz >> 3) * BM;

    f32x16 acc[4][2] = {};

    // prologue: tile0 (B then A) -> buf0 ; tile1 B -> buf1.  12 loads/thread in flight.
    stage_half_tile(smem + 32768,              Bt + (size_t)(n0      ) * F_SZ, 0, tid);
    stage_half_tile(smem + 32768 + HALF_BYTES, Bt + (size_t)(n0 + 128) * F_SZ, 0, tid);
    stage_half_tile(smem,                      A  + (size_t)(m0      ) * F_SZ, 0, tid);
    stage_half_tile(smem + HALF_BYTES,         A  + (size_t)(m0 + 128) * F_SZ, 0, tid);
    stage_half_tile(smem + BUF_BYTES + 32768,              Bt + (size_t)(n0      ) * F_SZ, BK, tid);
    stage_half_tile(smem + BUF_BYTES + 32768 + HALF_BYTES, Bt + (size_t)(n0 + 128) * F_SZ, BK, tid);
    asm volatile("s_waitcnt vmcnt(4)" ::: "memory");   // tile0 done, tile1.B in flight
    sbar();

    #pragma unroll 1
    for (int kt = 0; kt < NT; ++kt) {
        const int cur = kt & 1;
        const int nxt = cur ^ 1;
        unsigned char* const As = smem + cur * BUF_BYTES;
        unsigned char* const Bs = As + 32768;

        auto read_af = [&](i32x8* dst, int mi) {
            const int ra = wm * 128 + mi * 32 + l31;
            #pragma unroll
            for (int s = 0; s < 2; ++s) {
                const int ua = s * 4 + kh * 2;
                ((int4*)&dst[s])[0] = *(const int4*)(As + ra * BK + (((ua + 0) ^ (ra & 7)) * 16));
                ((int4*)&dst[s])[1] = *(const int4*)(As + ra * BK + (((ua + 1) ^ (ra & 7)) * 16));
            }
        };

        // phase 0 operands: all B frags + A strip 0
        i32x8 bq[2][2];
        #pragma unroll
        for (int ni = 0; ni < 2; ++ni) {
            const int rb = wn * 64 + ni * 32 + l31;
            #pragma unroll
            for (int s = 0; s < 2; ++s) {
                const int ua = s * 4 + kh * 2;
                ((int4*)&bq[ni][s])[0] = *(const int4*)(Bs + rb * BK + (((ua + 0) ^ (rb & 7)) * 16));
                ((int4*)&bq[ni][s])[1] = *(const int4*)(Bs + rb * BK + (((ua + 1) ^ (rb & 7)) * 16));
            }
        }
        i32x8 af[2][2];
        read_af(af[0], 0);

        #pragma unroll
        for (int mi = 0; mi < 4; ++mi) {
            if (mi < 3) read_af(af[(mi + 1) & 1], mi + 1);   // hide ds_read latency under MFMA

            if (mi == 0 && kt < NT - 1)
                stage_half_tile(smem + nxt * BUF_BYTES,              A  + (size_t)(m0      ) * F_SZ, (kt + 1) * BK, tid);
            if (mi == 1 && kt < NT - 1)
                stage_half_tile(smem + nxt * BUF_BYTES + HALF_BYTES, A  + (size_t)(m0 + 128) * F_SZ, (kt + 1) * BK, tid);
            if (mi == 2 && kt < NT - 2)
                stage_half_tile(smem + cur * BUF_BYTES + 32768,              Bt + (size_t)(n0      ) * F_SZ, (kt + 2) * BK, tid);
            if (mi == 3 && kt < NT - 2)
                stage_half_tile(smem + cur * BUF_BYTES + 32768 + HALF_BYTES, Bt + (size_t)(n0 + 128) * F_SZ, (kt + 2) * BK, tid);

            __builtin_amdgcn_sched_barrier(0);
            __builtin_amdgcn_s_setprio(1);
            #pragma unroll
            for (int ni = 0; ni < 2; ++ni)
                #pragma unroll
                for (int s = 0; s < 2; ++s)
                    acc[mi][ni] = __builtin_amdgcn_mfma_scale_f32_32x32x64_f8f6f4(
                        af[mi & 1][s], bq[ni][s], acc[mi][ni],
                        0 /*A fmt e4m3*/, 0 /*B fmt e4m3*/,
                        0, 0x7f7f7f7f,   /* opsel_a, scale_a = 2^0 */
                        0, 0x7f7f7f7f);  /* opsel_b, scale_b = 2^0 */
            __builtin_amdgcn_s_setprio(0);
            if (mi < 3) sbar();
        }

        if (kt <= NT - 3)      { asm volatile("s_waitcnt vmcnt(4)" ::: "memory"); }
        else if (kt == NT - 2) { asm volatile("s_waitcnt vmcnt(0)" ::: "memory"); }
        sbar();
    }

    // epilogue: 32x32 C/D layout col=lane&31, row=(r&3)+8*(r>>2)+4*(lane>>5)  (m74/m101-verified)
    float bv[2];
    #pragma unroll
    for (int ni = 0; ni < 2; ++ni) bv[ni] = bias[n0 + wn * 64 + ni * 32 + l31];
    #pragma unroll
    for (int mi = 0; mi < 4; ++mi) {
        const int gmb = m0 + wm * 128 + mi * 32 + 4 * kh;
        #pragma unroll
        for (int r = 0; r < 16; ++r) {
            const int grow = gmb + (r & 3) + 8 * (r >> 2);
            float p = 0.f;
            #pragma unroll
            for (int ni = 0; ni < 2; ++ni) {
                const int gn = n0 + wn * 64 + ni * 32 + l31;
                const float val = acc[mi][ni][r] * (1.0f / 256.0f) + bv[ni];
                C[(size_t)grow * H_SZ + gn] = __float2bfloat16(val);
                p += val * val;
            }
            // cross-lane: sum over the 32 col-lanes (masks<32 stay in-half)
            p += __shfl_xor(p, 1, 64);
            p += __shfl_xor(p, 2, 64);
            p += __shfl_xor(p, 4, 64);
            p += __shfl_xor(p, 8, 64);
            p += __shfl_xor(p, 16, 64);
            if (l31 == 0) atomicAdd(ss + grow, p);
        }
    }
}

// ---------------- LIF scan: 4 columns/thread, inv-norm in LDS, 3-deep load pipeline ----------------
__global__ __launch_bounds__(256) void lif_scan_kernel(const __hip_bfloat16* __restrict__ cur, // [M_SZ,H_SZ]
                                                       const float* __restrict__ ss,           // [M_SZ] sum-of-squares
                                                       float* __restrict__ spk,                // [T,B,H]
                                                       float* __restrict__ cnt)                // [B,H]
{
    __shared__ float s_inv[T_SZ];
    const int gid = blockIdx.x * 256 + threadIdx.x;     // 262144 threads
    const int b   = gid >> 9;                           // uniform within a block
    const int h0  = (gid & 511) * 4;

    // hoist the 32 identical sqrt/div per b out of every thread (bit-identical expr)
    if (threadIdx.x < T_SZ)
        s_inv[threadIdx.x] = 1.0f / fmaxf(sqrtf(ss[threadIdx.x * B_SZ + b]), 1e-12f);
    __syncthreads();

    const size_t stride = (size_t)B_SZ * H_SZ;
    const size_t base   = (size_t)b * H_SZ + h0;
    const __hip_bfloat16* p = cur + base;

    // 3-deep explicit prefetch: >=3 loads/wave in flight hides ~900cy HBM latency
    ushort4 pk[3];
    pk[0] = *(const ushort4*)(p);
    pk[1] = *(const ushort4*)(p + stride);
    pk[2] = *(const ushort4*)(p + 2 * stride);

    float v[4]  = {0, 0, 0, 0};
    float cn[4] = {0, 0, 0, 0};
    #pragma unroll
    for (int t = 0; t < T_SZ; ++t) {
        const ushort4 k = pk[t % 3];                    // t compile-time after unroll
        if (t + 3 < T_SZ) pk[t % 3] = *(const ushort4*)(p + (size_t)(t + 3) * stride);
        const float inv = s_inv[t];                     // LDS broadcast, conflict-free
        float so[4];
        {
            float c;
            c = bf16_bits_to_f32(k.x) * inv; v[0] += (c - v[0]) * 0.5f;
            c = bf16_bits_to_f32(k.y) * inv; v[1] += (c - v[1]) * 0.5f;
            c = bf16_bits_to_f32(k.z) * inv; v[2] += (c - v[2]) * 0.5f;
            c = bf16_bits_to_f32(k.w) * inv; v[3] += (c - v[3]) * 0.5f;
        }
        #pragma unroll
        for (int j = 0; j < 4; ++j) {
            float s = (v[j] >= 1.0f) ? 1.0f : 0.0f;     // Heaviside(v - v_th)
            so[j] = s;
            cn[j] += s;
            v[j] = (s != 0.f) ? 0.f : v[j];             // hard reset, detach
        }
        *(float4*)(spk + base + (size_t)t * stride) = make_float4(so[0], so[1], so[2], so[3]);
    }
    *(float4*)(cnt + base) = make_float4(cn[0], cn[1], cn[2], cn[3]);
}

extern "C" void kernel_launch(void* const* d_in, const int* in_sizes, int n_in,
                              void* d_out, int out_size, void* d_ws, size_t ws_size,
                              hipStream_t stream) {
    const float* x    = (const float*)d_in[0];   // [T,B,F] fp32
    const float* W    = (const float*)d_in[1];   // [H,F]  fp32
    const float* bias = (const float*)d_in[2];   // [H]    fp32

    float* spk = (float*)d_out;                          // [T,B,H]
    float* cnt = spk + (size_t)T_SZ * B_SZ * H_SZ;       // [B,H]

    char* ws = (char*)d_ws;
    unsigned char* x8    = (unsigned char*)ws;                                   // 33.5 MB
    unsigned char* W8    = x8 + (size_t)M_SZ * F_SZ;                             // 4.2 MB
    __hip_bfloat16* curb = (__hip_bfloat16*)(W8 + (size_t)H_SZ * F_SZ);          // 67.1 MB
    float* ss            = (float*)((char*)curb + (size_t)M_SZ * H_SZ * 2);      // 64 KB

    init_ss_kernel<<<M_SZ / 1024, 256, 0, stream>>>((float4*)ss);
    cvt_fp8_kernel<<<(M_SZ * F_SZ / 8) / 256, 256, 0, stream>>>(x, (unsigned int*)x8, 1.0f,   M_SZ * F_SZ / 8);
    cvt_fp8_kernel<<<(H_SZ * F_SZ / 8) / 256, 256, 0, stream>>>(W, (unsigned int*)W8, 256.0f, H_SZ * F_SZ / 8);
    gemm_fp8_kernel<<<dim3(H_SZ / BN, M_SZ / BM), 512, 0, stream>>>(x8, W8, bias, curb, ss);
    lif_scan_kernel<<<(B_SZ * H_SZ / 4) / 256, 256, 0, stream>>>(curb, ss, spk, cnt);
}